// Round 1
// baseline (42.552 us; speedup 1.0000x reference)
//
#include <hip/hip_runtime.h>
#include <math.h>

#define NUM_ANCHORS 5
#define NUM_CLASSES 80
#define FM_H 19
#define FM_W 19
#define MAX_OBJECT 50
#define HW (FM_H * FM_W)                 // 361
#define CELLS_PER_B (NUM_ANCHORS * HW)   // 1805
#define CH (5 + NUM_CLASSES)             // 85
#define BLOCKS_PER_B ((CELLS_PER_B + 255) / 256)  // 8
#define NOOBJECT_SCALE 1.0f
#define OBJECT_SCALE 5.0f
#define BACKGROUND_THRESHOLD 0.6f

struct GTEntry {
    float gx, gy, gw, gh;   // gt box in feature-map units
    float tx, ty, tw, th;   // regression targets
    int   acell;            // best_n*HW + gj*W + gi, or -1 if invalid
    int   cls;              // target class index
};

__device__ inline float iou_cwh(float ax, float ay, float aw, float ah,
                                float bx, float by, float bw, float bh) {
    float ax1 = ax - aw * 0.5f, ax2 = ax + aw * 0.5f;
    float ay1 = ay - ah * 0.5f, ay2 = ay + ah * 0.5f;
    float bx1 = bx - bw * 0.5f, bx2 = bx + bw * 0.5f;
    float by1 = by - bh * 0.5f, by2 = by + bh * 0.5f;
    float uw = fmaxf(ax2, bx2) - fminf(ax1, bx1);
    float uh = fmaxf(ay2, by2) - fminf(ay1, by1);
    float cw = aw + bw - uw;
    float chh = ah + bh - uh;
    float inter = (cw > 0.0f && chh > 0.0f) ? cw * chh : 0.0f;
    float uni = aw * ah + bw * bh - inter;
    return inter / fmaxf(uni, 1e-12f);
}

__device__ inline float sigmoidf(float v) { return 1.0f / (1.0f + expf(-v)); }

__global__ __launch_bounds__(256) void yolov2_loss_kernel(
    const float* __restrict__ out,      // (B, A*CH, H, W)
    const float* __restrict__ target,   // (B, T*5)
    const float* __restrict__ anchors,  // (A, 2)
    float* __restrict__ loss)           // scalar
{
    const int b    = blockIdx.x / BLOCKS_PER_B;
    const int blk  = blockIdx.x % BLOCKS_PER_B;
    const int cell = blk * 256 + threadIdx.x;   // 0 .. CELLS_PER_B-1

    __shared__ float tg[MAX_OBJECT * 5];
    __shared__ float anc[NUM_ANCHORS * 2];
    __shared__ GTEntry g[MAX_OBJECT];
    __shared__ float wsum[4];

    // stage target row + anchors
    for (int i = threadIdx.x; i < MAX_OBJECT * 5; i += blockDim.x)
        tg[i] = target[b * MAX_OBJECT * 5 + i];
    if (threadIdx.x < NUM_ANCHORS * 2)
        anc[threadIdx.x] = anchors[threadIdx.x];
    __syncthreads();

    // per-GT precompute (threads 0..49)
    if (threadIdx.x < MAX_OBJECT) {
        const int t = threadIdx.x;
        // validity = cumprod(x != 0) -> prefix property
        bool valid = true;
        for (int s = 0; s <= t; ++s) valid = valid && (tg[s * 5 + 1] != 0.0f);
        float cls = tg[t * 5 + 0];
        float gx = tg[t * 5 + 1] * (float)FM_W;
        float gy = tg[t * 5 + 2] * (float)FM_H;
        float gw = tg[t * 5 + 3] * (float)FM_W;
        float gh = tg[t * 5 + 4] * (float)FM_H;
        // best anchor by wh-IoU (first max wins, like argmax)
        int bn = 0; float best = -1.0f;
        for (int a = 0; a < NUM_ANCHORS; ++a) {
            float aw = anc[2 * a], ah = anc[2 * a + 1];
            float inter = fminf(gw, aw) * fminf(gh, ah);
            float uni = gw * gh + aw * ah - inter;
            float r = inter / fmaxf(uni, 1e-12f);
            if (r > best) { best = r; bn = a; }
        }
        int gi = (int)gx; gi = gi < 0 ? 0 : (gi > FM_W - 1 ? FM_W - 1 : gi);
        int gj = (int)gy; gj = gj < 0 ? 0 : (gj > FM_H - 1 ? FM_H - 1 : gj);
        GTEntry e;
        e.gx = gx; e.gy = gy; e.gw = gw; e.gh = gh;
        e.tx = gx - (float)gi;
        e.ty = gy - (float)gj;
        e.tw = logf(fmaxf(gw, 1e-12f) / anc[2 * bn]);
        e.th = logf(fmaxf(gh, 1e-12f) / anc[2 * bn + 1]);
        e.acell = valid ? (bn * HW + gj * FM_W + gi) : -1;
        e.cls = (int)cls;
        g[t] = e;
    }
    __syncthreads();

    float local = 0.0f;
    if (cell < CELLS_PER_B) {
        const int a  = cell / HW;
        const int hw = cell - a * HW;
        const int hrow = hw / FM_W;
        const int wcol = hw - hrow * FM_W;

        const float* base = out + ((size_t)b * NUM_ANCHORS * CH + (size_t)a * CH) * HW + hw;
        float ox = base[0 * HW];
        float oy = base[1 * HW];
        float ow = base[2 * HW];
        float oh = base[3 * HW];
        float oc = base[4 * HW];

        float x = sigmoidf(ox);
        float y = sigmoidf(oy);
        float conf = sigmoidf(oc);
        float px = x + (float)wcol;
        float py = y + (float)hrow;
        float pw = expf(ow) * anc[2 * a];
        float ph = expf(oh) * anc[2 * a + 1];

        float best_iou = 0.0f;
        int   last_t = -1;
        float tconf = 0.0f;
        for (int t = 0; t < MAX_OBJECT; ++t) {
            if (g[t].acell < 0) break;   // validity is a prefix
            float iou = iou_cwh(g[t].gx, g[t].gy, g[t].gw, g[t].gh, px, py, pw, ph);
            best_iou = fmaxf(best_iou, iou);
            if (g[t].acell == cell) { last_t = t; tconf = iou; }
        }

        if (last_t >= 0) {
            // object cell: conf weighted by OBJECT_SCALE, coord + class terms
            float dc = conf - tconf;
            local += 0.5f * OBJECT_SCALE * dc * dc;
            float dx = x  - g[last_t].tx; local += 0.5f * dx * dx;
            float dy = y  - g[last_t].ty; local += 0.5f * dy * dy;
            float dw = ow - g[last_t].tw; local += 0.5f * dw * dw;
            float dh = oh - g[last_t].th; local += 0.5f * dh * dh;
            // class cross-entropy: lse(logits) - logit[cls]
            const float* cl = base + 5 * HW;
            float mx = -INFINITY;
            for (int c = 0; c < NUM_CLASSES; ++c) mx = fmaxf(mx, cl[c * HW]);
            float s = 0.0f;
            for (int c = 0; c < NUM_CLASSES; ++c) s += expf(cl[c * HW] - mx);
            float lse = mx + logf(s);
            local += (lse - cl[g[last_t].cls * HW]);
        } else {
            // background: contributes conf^2/2 unless best_iou > threshold
            if (!(best_iou > BACKGROUND_THRESHOLD))
                local += 0.5f * NOOBJECT_SCALE * conf * conf;
        }
    }

    // wave (64-lane) reduce, then cross-wave via LDS
    for (int off = 32; off > 0; off >>= 1)
        local += __shfl_down(local, off, 64);
    const int lane = threadIdx.x & 63;
    const int wid  = threadIdx.x >> 6;
    if (lane == 0) wsum[wid] = local;
    __syncthreads();
    if (threadIdx.x == 0) {
        float tot = wsum[0] + wsum[1] + wsum[2] + wsum[3];
        atomicAdd(loss, tot);
    }
}

extern "C" void kernel_launch(void* const* d_in, const int* in_sizes, int n_in,
                              void* d_out, int out_size, void* d_ws, size_t ws_size,
                              hipStream_t stream) {
    const float* out_t   = (const float*)d_in[0];
    const float* target  = (const float*)d_in[1];
    const float* anchors = (const float*)d_in[2];
    float* loss = (float*)d_out;

    const int B = in_sizes[1] / (MAX_OBJECT * 5);

    hipMemsetAsync(d_out, 0, sizeof(float), stream);
    yolov2_loss_kernel<<<dim3(B * BLOCKS_PER_B), dim3(256), 0, stream>>>(
        out_t, target, anchors, loss);
}

// Round 2
// 21.409 us; speedup vs baseline: 1.9875x; 1.9875x over previous
//
#include <hip/hip_runtime.h>
#include <math.h>

#define NUM_ANCHORS 5
#define NUM_CLASSES 80
#define FM_H 19
#define FM_W 19
#define MAX_OBJECT 50
#define HW (FM_H * FM_W)                 // 361
#define CELLS_PER_B (NUM_ANCHORS * HW)   // 1805
#define CH (5 + NUM_CLASSES)             // 85
#define BLOCKS_PER_B ((CELLS_PER_B + 255) / 256)  // 8
#define NOOBJECT_SCALE 1.0f
#define OBJECT_SCALE 5.0f
#define BACKGROUND_THRESHOLD 0.6f

struct GTEntry {
    float gx, gy, gw, gh;   // gt box in feature-map units
    float tx, ty, tw, th;   // regression targets
    int   acell;            // best_n*HW + gj*W + gi
    int   cls;              // target class index
};

__device__ inline float frcp(float v) { return __builtin_amdgcn_rcpf(v); }
__device__ inline float fsigmoid(float v) { return frcp(1.0f + __expf(-v)); }

__device__ inline float iou_cwh(float ax, float ay, float aw, float ah,
                                float bx, float by, float bw, float bh) {
    float ax1 = ax - aw * 0.5f, ax2 = ax + aw * 0.5f;
    float ay1 = ay - ah * 0.5f, ay2 = ay + ah * 0.5f;
    float bx1 = bx - bw * 0.5f, bx2 = bx + bw * 0.5f;
    float by1 = by - bh * 0.5f, by2 = by + bh * 0.5f;
    float uw = fmaxf(ax2, bx2) - fminf(ax1, bx1);
    float uh = fmaxf(ay2, by2) - fminf(ay1, by1);
    float cw = aw + bw - uw;
    float chh = ah + bh - uh;
    float inter = (cw > 0.0f && chh > 0.0f) ? cw * chh : 0.0f;
    float uni = aw * ah + bw * bh - inter;
    return inter * frcp(fmaxf(uni, 1e-12f));
}

__global__ __launch_bounds__(256) void yolov2_loss_kernel(
    const float* __restrict__ out,      // (B, A*CH, H, W)
    const float* __restrict__ target,   // (B, T*5)
    const float* __restrict__ anchors,  // (A, 2)
    float* __restrict__ loss)           // scalar
{
    const int b    = blockIdx.x / BLOCKS_PER_B;
    const int blk  = blockIdx.x % BLOCKS_PER_B;
    const int cell = blk * 256 + threadIdx.x;   // 0 .. CELLS_PER_B-1

    __shared__ float tg[MAX_OBJECT * 5];
    __shared__ float anc[NUM_ANCHORS * 2];
    __shared__ GTEntry g[MAX_OBJECT];
    __shared__ int   nv_sh;
    __shared__ float wsum[4];

    // stage target row + anchors
    for (int i = threadIdx.x; i < MAX_OBJECT * 5; i += blockDim.x)
        tg[i] = target[b * MAX_OBJECT * 5 + i];
    if (threadIdx.x < NUM_ANCHORS * 2)
        anc[threadIdx.x] = anchors[threadIdx.x];
    __syncthreads();

    // validity is a prefix (setup zeroes t >= nvalid, x in [0.1,0.9] otherwise):
    // wave 0 computes nv via ballot
    if (threadIdx.x < 64) {
        unsigned long long m =
            __ballot(threadIdx.x < MAX_OBJECT && tg[threadIdx.x * 5 + 1] != 0.0f);
        if (threadIdx.x == 0) nv_sh = __popcll(m);
    }

    // per-GT precompute (threads 0..49)
    if (threadIdx.x < MAX_OBJECT) {
        const int t = threadIdx.x;
        float cls = tg[t * 5 + 0];
        float gx = tg[t * 5 + 1] * (float)FM_W;
        float gy = tg[t * 5 + 2] * (float)FM_H;
        float gw = tg[t * 5 + 3] * (float)FM_W;
        float gh = tg[t * 5 + 4] * (float)FM_H;
        // best anchor by wh-IoU (first max wins, like argmax)
        int bn = 0; float best = -1.0f;
        #pragma unroll
        for (int a = 0; a < NUM_ANCHORS; ++a) {
            float aw = anc[2 * a], ah = anc[2 * a + 1];
            float inter = fminf(gw, aw) * fminf(gh, ah);
            float uni = gw * gh + aw * ah - inter;
            float r = inter * frcp(fmaxf(uni, 1e-12f));
            if (r > best) { best = r; bn = a; }
        }
        int gi = (int)gx; gi = gi < 0 ? 0 : (gi > FM_W - 1 ? FM_W - 1 : gi);
        int gj = (int)gy; gj = gj < 0 ? 0 : (gj > FM_H - 1 ? FM_H - 1 : gj);
        GTEntry e;
        e.gx = gx; e.gy = gy; e.gw = gw; e.gh = gh;
        e.tx = gx - (float)gi;
        e.ty = gy - (float)gj;
        e.tw = logf(fmaxf(gw, 1e-12f) * frcp(anc[2 * bn]));
        e.th = logf(fmaxf(gh, 1e-12f) * frcp(anc[2 * bn + 1]));
        e.acell = bn * HW + gj * FM_W + gi;
        e.cls = (int)cls;
        g[t] = e;
    }
    __syncthreads();

    const int nv = nv_sh;   // block-uniform trip count

    float local = 0.0f;
    if (cell < CELLS_PER_B) {
        const int a  = cell / HW;
        const int hw = cell - a * HW;
        const int hrow = hw / FM_W;
        const int wcol = hw - hrow * FM_W;

        const float* base = out + ((size_t)b * NUM_ANCHORS * CH + (size_t)a * CH) * HW + hw;
        float ox = base[0 * HW];
        float oy = base[1 * HW];
        float ow = base[2 * HW];
        float oh = base[3 * HW];
        float oc = base[4 * HW];

        float x = fsigmoid(ox);
        float y = fsigmoid(oy);
        float conf = fsigmoid(oc);
        float px = x + (float)wcol;
        float py = y + (float)hrow;
        float pw = __expf(ow) * anc[2 * a];
        float ph = __expf(oh) * anc[2 * a + 1];

        float best_iou = 0.0f;
        int   last_t = -1;
        float tconf = 0.0f;
        #pragma unroll 5
        for (int t = 0; t < nv; ++t) {
            float iou = iou_cwh(g[t].gx, g[t].gy, g[t].gw, g[t].gh, px, py, pw, ph);
            best_iou = fmaxf(best_iou, iou);
            bool match = (g[t].acell == cell);
            last_t = match ? t : last_t;
            tconf  = match ? iou : tconf;
        }

        if (last_t >= 0) {
            // object cell: conf weighted by OBJECT_SCALE, coord + class terms
            float dc = conf - tconf;
            local += 0.5f * OBJECT_SCALE * dc * dc;
            float dx = x  - g[last_t].tx; local += 0.5f * dx * dx;
            float dy = y  - g[last_t].ty; local += 0.5f * dy * dy;
            float dw = ow - g[last_t].tw; local += 0.5f * dw * dw;
            float dh = oh - g[last_t].th; local += 0.5f * dh * dh;
            // class cross-entropy via 4-way interleaved online softmax
            const float* cl = base + 5 * HW;
            float tlogit = cl[g[last_t].cls * HW];
            float mx0 = -INFINITY, mx1 = -INFINITY, mx2 = -INFINITY, mx3 = -INFINITY;
            float s0 = 0.f, s1 = 0.f, s2 = 0.f, s3 = 0.f;
            #pragma unroll
            for (int c = 0; c < NUM_CLASSES; c += 4) {
                float v0 = cl[(c + 0) * HW];
                float v1 = cl[(c + 1) * HW];
                float v2 = cl[(c + 2) * HW];
                float v3 = cl[(c + 3) * HW];
                float m0 = fmaxf(mx0, v0); s0 = s0 * __expf(mx0 - m0) + __expf(v0 - m0); mx0 = m0;
                float m1 = fmaxf(mx1, v1); s1 = s1 * __expf(mx1 - m1) + __expf(v1 - m1); mx1 = m1;
                float m2 = fmaxf(mx2, v2); s2 = s2 * __expf(mx2 - m2) + __expf(v2 - m2); mx2 = m2;
                float m3 = fmaxf(mx3, v3); s3 = s3 * __expf(mx3 - m3) + __expf(v3 - m3); mx3 = m3;
            }
            float mA = fmaxf(fmaxf(mx0, mx1), fmaxf(mx2, mx3));
            float s = s0 * __expf(mx0 - mA) + s1 * __expf(mx1 - mA)
                    + s2 * __expf(mx2 - mA) + s3 * __expf(mx3 - mA);
            float lse = mA + __logf(s);
            local += (lse - tlogit);
        } else {
            // background: contributes conf^2/2 unless best_iou > threshold
            if (!(best_iou > BACKGROUND_THRESHOLD))
                local += 0.5f * NOOBJECT_SCALE * conf * conf;
        }
    }

    // wave (64-lane) reduce, then cross-wave via LDS
    for (int off = 32; off > 0; off >>= 1)
        local += __shfl_down(local, off, 64);
    const int lane = threadIdx.x & 63;
    const int wid  = threadIdx.x >> 6;
    if (lane == 0) wsum[wid] = local;
    __syncthreads();
    if (threadIdx.x == 0) {
        float tot = wsum[0] + wsum[1] + wsum[2] + wsum[3];
        atomicAdd(loss, tot);
    }
}

extern "C" void kernel_launch(void* const* d_in, const int* in_sizes, int n_in,
                              void* d_out, int out_size, void* d_ws, size_t ws_size,
                              hipStream_t stream) {
    const float* out_t   = (const float*)d_in[0];
    const float* target  = (const float*)d_in[1];
    const float* anchors = (const float*)d_in[2];
    float* loss = (float*)d_out;

    const int B = in_sizes[1] / (MAX_OBJECT * 5);

    hipMemsetAsync(d_out, 0, sizeof(float), stream);
    yolov2_loss_kernel<<<dim3(B * BLOCKS_PER_B), dim3(256), 0, stream>>>(
        out_t, target, anchors, loss);
}

// Round 3
// 18.785 us; speedup vs baseline: 2.2652x; 1.1397x over previous
//
#include <hip/hip_runtime.h>
#include <math.h>

#define NUM_ANCHORS 5
#define NUM_CLASSES 80
#define FM_H 19
#define FM_W 19
#define MAX_OBJECT 50
#define HW (FM_H * FM_W)                 // 361
#define CELLS_PER_B (NUM_ANCHORS * HW)   // 1805
#define CH (5 + NUM_CLASSES)             // 85
#define BLOCKS_PER_B ((CELLS_PER_B + 255) / 256)  // 8
#define NOOBJECT_SCALE 1.0f
#define OBJECT_SCALE 5.0f
#define BACKGROUND_THRESHOLD 0.6f

struct GTEntry {
    float gx, gy, gw, gh;   // gt box in feature-map units
    float tx, ty, tw, th;   // regression targets
    int   acell;            // best_n*HW + gj*W + gi
    int   cls;              // target class index
};

__device__ inline float frcp(float v) { return __builtin_amdgcn_rcpf(v); }
__device__ inline float fsigmoid(float v) { return frcp(1.0f + __expf(-v)); }

__device__ inline float iou_cwh(float ax, float ay, float aw, float ah,
                                float bx, float by, float bw, float bh) {
    float ax1 = ax - aw * 0.5f, ax2 = ax + aw * 0.5f;
    float ay1 = ay - ah * 0.5f, ay2 = ay + ah * 0.5f;
    float bx1 = bx - bw * 0.5f, bx2 = bx + bw * 0.5f;
    float by1 = by - bh * 0.5f, by2 = by + bh * 0.5f;
    float uw = fmaxf(ax2, bx2) - fminf(ax1, bx1);
    float uh = fmaxf(ay2, by2) - fminf(ay1, by1);
    float cw = aw + bw - uw;
    float chh = ah + bh - uh;
    float inter = (cw > 0.0f && chh > 0.0f) ? cw * chh : 0.0f;
    float uni = aw * ah + bw * bh - inter;
    return inter * frcp(fmaxf(uni, 1e-12f));
}

__global__ __launch_bounds__(256) void yolov2_main(
    const float* __restrict__ out,      // (B, A*CH, H, W)
    const float* __restrict__ target,   // (B, T*5)
    const float* __restrict__ anchors,  // (A, 2)
    float* __restrict__ partial)        // one float per block
{
    const int b    = blockIdx.x / BLOCKS_PER_B;
    const int blk  = blockIdx.x % BLOCKS_PER_B;
    const int cell = blk * 256 + threadIdx.x;   // 0 .. CELLS_PER_B-1
    const int lane = threadIdx.x & 63;
    const int wid  = threadIdx.x >> 6;

    __shared__ float tg[MAX_OBJECT * 5];
    __shared__ float anc[NUM_ANCHORS * 2];
    __shared__ GTEntry g[MAX_OBJECT];
    __shared__ int   nv_sh;
    __shared__ int   n_obj;
    __shared__ int   entries[MAX_OBJECT];   // distinct acells <= nvalid <= 50
    __shared__ float wsum[4];

    // stage target row + anchors, init counters
    for (int i = threadIdx.x; i < MAX_OBJECT * 5; i += blockDim.x)
        tg[i] = target[b * MAX_OBJECT * 5 + i];
    if (threadIdx.x < NUM_ANCHORS * 2)
        anc[threadIdx.x] = anchors[threadIdx.x];
    if (threadIdx.x == 0) n_obj = 0;
    __syncthreads();

    // validity is a prefix (cumprod); wave 0 computes nv via ballot
    if (threadIdx.x < 64) {
        unsigned long long m =
            __ballot(threadIdx.x < MAX_OBJECT && tg[threadIdx.x * 5 + 1] != 0.0f);
        if (threadIdx.x == 0) nv_sh = __popcll(m);
    }

    // per-GT precompute (threads 0..49)
    if (threadIdx.x < MAX_OBJECT) {
        const int t = threadIdx.x;
        float cls = tg[t * 5 + 0];
        float gx = tg[t * 5 + 1] * (float)FM_W;
        float gy = tg[t * 5 + 2] * (float)FM_H;
        float gw = tg[t * 5 + 3] * (float)FM_W;
        float gh = tg[t * 5 + 4] * (float)FM_H;
        int bn = 0; float best = -1.0f;
        #pragma unroll
        for (int a = 0; a < NUM_ANCHORS; ++a) {
            float aw = anc[2 * a], ah = anc[2 * a + 1];
            float inter = fminf(gw, aw) * fminf(gh, ah);
            float uni = gw * gh + aw * ah - inter;
            float r = inter * frcp(fmaxf(uni, 1e-12f));
            if (r > best) { best = r; bn = a; }
        }
        int gi = (int)gx; gi = gi < 0 ? 0 : (gi > FM_W - 1 ? FM_W - 1 : gi);
        int gj = (int)gy; gj = gj < 0 ? 0 : (gj > FM_H - 1 ? FM_H - 1 : gj);
        GTEntry e;
        e.gx = gx; e.gy = gy; e.gw = gw; e.gh = gh;
        e.tx = gx - (float)gi;
        e.ty = gy - (float)gj;
        e.tw = logf(fmaxf(gw, 1e-12f) * frcp(anc[2 * bn]));
        e.th = logf(fmaxf(gh, 1e-12f) * frcp(anc[2 * bn + 1]));
        e.acell = bn * HW + gj * FM_W + gi;
        e.cls = (int)cls;
        g[t] = e;
    }
    __syncthreads();

    const int nv = nv_sh;   // block-uniform trip count

    float local = 0.0f;
    if (cell < CELLS_PER_B) {
        const int a  = cell / HW;
        const int hw = cell - a * HW;
        const int hrow = hw / FM_W;
        const int wcol = hw - hrow * FM_W;

        const float* base = out + ((size_t)b * NUM_ANCHORS * CH + (size_t)a * CH) * HW + hw;
        float ox = base[0 * HW];
        float oy = base[1 * HW];
        float ow = base[2 * HW];
        float oh = base[3 * HW];
        float oc = base[4 * HW];

        float x = fsigmoid(ox);
        float y = fsigmoid(oy);
        float conf = fsigmoid(oc);
        float px = x + (float)wcol;
        float py = y + (float)hrow;
        float pw = __expf(ow) * anc[2 * a];
        float ph = __expf(oh) * anc[2 * a + 1];

        float best_iou = 0.0f;
        int   last_t = -1;
        float tconf = 0.0f;
        #pragma unroll 5
        for (int t = 0; t < nv; ++t) {
            float iou = iou_cwh(g[t].gx, g[t].gy, g[t].gw, g[t].gh, px, py, pw, ph);
            best_iou = fmaxf(best_iou, iou);
            bool match = (g[t].acell == cell);
            last_t = match ? t : last_t;
            tconf  = match ? iou : tconf;
        }

        if (last_t >= 0) {
            // object cell: conf term (OBJECT_SCALE) + coord terms; CE deferred
            float dc = conf - tconf;
            local += 0.5f * OBJECT_SCALE * dc * dc;
            float dx = x  - g[last_t].tx; local += 0.5f * dx * dx;
            float dy = y  - g[last_t].ty; local += 0.5f * dy * dy;
            float dw = ow - g[last_t].tw; local += 0.5f * dw * dw;
            float dh = oh - g[last_t].th; local += 0.5f * dh * dh;
            int pos = atomicAdd(&n_obj, 1);
            entries[pos] = cell | (g[last_t].cls << 16);
        } else {
            if (!(best_iou > BACKGROUND_THRESHOLD))
                local += 0.5f * NOOBJECT_SCALE * conf * conf;
        }
    }
    __syncthreads();

    // wave-cooperative class cross-entropy: one wave per object cell,
    // lanes 0..39 load 2 logits each (80 lines in flight, one latency)
    const int ne = n_obj;
    for (int e = wid; e < ne; e += 4) {
        int pk    = entries[e];
        int ecell = pk & 0xFFFF;
        int ecls  = pk >> 16;
        int a  = ecell / HW;
        int hw = ecell - a * HW;
        const float* cl = out + ((size_t)b * NUM_ANCHORS * CH + (size_t)a * CH + 5) * HW + hw;
        float v0 = (lane < NUM_CLASSES / 2) ? cl[(2 * lane + 0) * HW] : -INFINITY;
        float v1 = (lane < NUM_CLASSES / 2) ? cl[(2 * lane + 1) * HW] : -INFINITY;
        float tl = cl[(size_t)ecls * HW];
        float m = fmaxf(v0, v1);
        #pragma unroll
        for (int off = 32; off > 0; off >>= 1)
            m = fmaxf(m, __shfl_xor(m, off, 64));
        float s = (lane < NUM_CLASSES / 2)
                    ? (__expf(v0 - m) + __expf(v1 - m)) : 0.0f;
        #pragma unroll
        for (int off = 32; off > 0; off >>= 1)
            s += __shfl_xor(s, off, 64);
        if (lane == 0) local += (m + __logf(s) - tl);
    }

    // wave reduce, cross-wave via LDS, one partial per block (no atomics)
    for (int off = 32; off > 0; off >>= 1)
        local += __shfl_down(local, off, 64);
    if (lane == 0) wsum[wid] = local;
    __syncthreads();
    if (threadIdx.x == 0)
        partial[blockIdx.x] = wsum[0] + wsum[1] + wsum[2] + wsum[3];
}

__global__ __launch_bounds__(256) void yolov2_reduce(
    const float* __restrict__ partial, int n, float* __restrict__ loss)
{
    __shared__ float wsum[4];
    float v = 0.0f;
    for (int i = threadIdx.x; i < n; i += 256) v += partial[i];
    for (int off = 32; off > 0; off >>= 1)
        v += __shfl_down(v, off, 64);
    const int lane = threadIdx.x & 63;
    const int wid  = threadIdx.x >> 6;
    if (lane == 0) wsum[wid] = v;
    __syncthreads();
    if (threadIdx.x == 0) loss[0] = wsum[0] + wsum[1] + wsum[2] + wsum[3];
}

extern "C" void kernel_launch(void* const* d_in, const int* in_sizes, int n_in,
                              void* d_out, int out_size, void* d_ws, size_t ws_size,
                              hipStream_t stream) {
    const float* out_t   = (const float*)d_in[0];
    const float* target  = (const float*)d_in[1];
    const float* anchors = (const float*)d_in[2];
    float* loss    = (float*)d_out;
    float* partial = (float*)d_ws;

    const int B = in_sizes[1] / (MAX_OBJECT * 5);
    const int nblocks = B * BLOCKS_PER_B;

    yolov2_main<<<dim3(nblocks), dim3(256), 0, stream>>>(out_t, target, anchors, partial);
    yolov2_reduce<<<dim3(1), dim3(256), 0, stream>>>(partial, nblocks, loss);
}

// Round 4
// 18.757 us; speedup vs baseline: 2.2686x; 1.0015x over previous
//
#include <hip/hip_runtime.h>
#include <math.h>

#define NUM_ANCHORS 5
#define NUM_CLASSES 80
#define FM_H 19
#define FM_W 19
#define MAX_OBJECT 50
#define HW (FM_H * FM_W)                 // 361
#define CELLS_PER_B (NUM_ANCHORS * HW)   // 1805
#define CH (5 + NUM_CLASSES)             // 85
#define BLOCKS_PER_B ((CELLS_PER_B + 255) / 256)  // 8
#define OBJECT_SCALE 5.0f
#define BACKGROUND_THRESHOLD 0.6f

__device__ inline float frcp(float v) { return __builtin_amdgcn_rcpf(v); }
__device__ inline float fsigmoid(float v) { return frcp(1.0f + __expf(-v)); }

__global__ __launch_bounds__(256) void yolov2_main(
    const float* __restrict__ out,      // (B, A*CH, H, W)
    const float* __restrict__ target,   // (B, T*5)
    const float* __restrict__ anchors,  // (A, 2)
    float* __restrict__ partial)        // one float per block
{
    const int b    = blockIdx.x / BLOCKS_PER_B;
    const int blk  = blockIdx.x % BLOCKS_PER_B;
    const int cell = blk * 256 + threadIdx.x;   // 0 .. CELLS_PER_B-1
    const int lane = threadIdx.x & 63;
    const int wid  = threadIdx.x >> 6;

    // GT SoA in LDS: two float4 per box for the hot loop
    __shared__ float4 gA[MAX_OBJECT];   // bx1, bx2, by1, by2
    __shared__ float4 gB[MAX_OBJECT];   // bw, bh, barea, acell(bits)
    __shared__ float4 gT[MAX_OBJECT];   // tx, ty, tw, th
    __shared__ int    gcls[MAX_OBJECT];
    __shared__ int    nv_sh, n_obj;
    __shared__ int    entries[MAX_OBJECT];
    __shared__ float  wsum[4];

    const bool incell = (cell < CELLS_PER_B);
    const int a    = incell ? (cell / HW) : 0;
    const int hw   = cell - a * HW;
    const int hrow = hw / FM_W;
    const int wcol = hw - hrow * FM_W;

    // ---- issue ALL global loads up front: HBM latency overlaps GT precompute
    const float* base = out + ((size_t)(b * NUM_ANCHORS + a) * CH) * HW + hw;
    float ox = 0.f, oy = 0.f, ow = 0.f, oh = 0.f, oc = 0.f;
    if (incell) {
        ox = base[0];
        oy = base[HW];
        ow = base[2 * HW];
        oh = base[3 * HW];
        oc = base[4 * HW];
    }
    const float anc_w = anchors[2 * a];
    const float anc_h = anchors[2 * a + 1];

    if (threadIdx.x == 0) n_obj = 0;

    // ---- wave 0: GT precompute straight from global (no LDS staging pass)
    if (threadIdx.x < 64) {
        const int t = threadIdx.x;
        float f0 = 0.f, f1 = 0.f, f2 = 0.f, f3 = 0.f, f4 = 0.f;
        if (t < MAX_OBJECT) {
            const float* tp = target + (size_t)b * MAX_OBJECT * 5 + t * 5;
            f0 = tp[0]; f1 = tp[1]; f2 = tp[2]; f3 = tp[3]; f4 = tp[4];
        }
        // validity is a prefix (cumprod of x!=0); popcount == prefix length
        unsigned long long m = __ballot(t < MAX_OBJECT && f1 != 0.0f);
        if (t == 0) nv_sh = __popcll(m);
        if (t < MAX_OBJECT) {
            float gx = f1 * (float)FM_W;
            float gy = f2 * (float)FM_H;
            float gw = f3 * (float)FM_W;
            float gh = f4 * (float)FM_H;
            int bn = 0; float best = -1.0f;
            #pragma unroll
            for (int k = 0; k < NUM_ANCHORS; ++k) {
                float aw = anchors[2 * k], ah = anchors[2 * k + 1];
                float inter = fminf(gw, aw) * fminf(gh, ah);
                float uni = gw * gh + aw * ah - inter;
                float r = inter * frcp(fmaxf(uni, 1e-12f));
                if (r > best) { best = r; bn = k; }
            }
            int gi = (int)gx; gi = gi < 0 ? 0 : (gi > FM_W - 1 ? FM_W - 1 : gi);
            int gj = (int)gy; gj = gj < 0 ? 0 : (gj > FM_H - 1 ? FM_H - 1 : gj);
            int acell = bn * HW + gj * FM_W + gi;
            gA[t] = make_float4(gx - gw * 0.5f, gx + gw * 0.5f,
                                gy - gh * 0.5f, gy + gh * 0.5f);
            gB[t] = make_float4(gw, gh, gw * gh, __int_as_float(acell));
            gT[t] = make_float4(gx - (float)gi, gy - (float)gj,
                                logf(fmaxf(gw, 1e-12f) * frcp(anchors[2 * bn])),
                                logf(fmaxf(gh, 1e-12f) * frcp(anchors[2 * bn + 1])));
            gcls[t] = (int)f0;
        }
    }
    __syncthreads();

    const int nv = nv_sh;   // block-uniform trip count
    float local = 0.0f;

    if (incell) {
        float x    = fsigmoid(ox);
        float y    = fsigmoid(oy);
        float conf = fsigmoid(oc);
        float px = x + (float)wcol;
        float py = y + (float)hrow;
        float pw = __expf(ow) * anc_w;
        float ph = __expf(oh) * anc_h;
        float ax1 = px - pw * 0.5f, ax2 = px + pw * 0.5f;
        float ay1 = py - ph * 0.5f, ay2 = py + ph * 0.5f;
        float parea = pw * ph;

        // hot loop: no divide, no running max — boolean threshold + match only
        bool bg_hit = false;
        int  last_t = -1;
        #pragma unroll 5
        for (int t = 0; t < nv; ++t) {
            float4 A  = gA[t];
            float4 Bv = gB[t];
            float uw = fmaxf(ax2, A.y) - fminf(ax1, A.x);
            float uh = fmaxf(ay2, A.w) - fminf(ay1, A.z);
            float cw  = Bv.x + pw - uw;
            float chh = Bv.y + ph - uh;
            float inter = (cw > 0.f && chh > 0.f) ? cw * chh : 0.f;
            float uni = parea + Bv.z - inter;
            bg_hit = bg_hit || (inter > BACKGROUND_THRESHOLD * uni);
            if (__float_as_int(Bv.w) == cell) last_t = t;
        }

        if (last_t >= 0) {
            // recompute full IoU once for the matched box
            float4 A  = gA[last_t];
            float4 Bv = gB[last_t];
            float4 Tt = gT[last_t];
            float uw = fmaxf(ax2, A.y) - fminf(ax1, A.x);
            float uh = fmaxf(ay2, A.w) - fminf(ay1, A.z);
            float cw  = Bv.x + pw - uw;
            float chh = Bv.y + ph - uh;
            float inter = (cw > 0.f && chh > 0.f) ? cw * chh : 0.f;
            float tconf = inter * frcp(fmaxf(parea + Bv.z - inter, 1e-12f));
            float dc = conf - tconf; local += 0.5f * OBJECT_SCALE * dc * dc;
            float dx = x  - Tt.x; local += 0.5f * dx * dx;
            float dy = y  - Tt.y; local += 0.5f * dy * dy;
            float dw = ow - Tt.z; local += 0.5f * dw * dw;
            float dh = oh - Tt.w; local += 0.5f * dh * dh;
            int pos = atomicAdd(&n_obj, 1);
            entries[pos] = cell | (gcls[last_t] << 16);
        } else if (!bg_hit) {
            local += 0.5f * conf * conf;
        }
    }
    __syncthreads();

    // wave-cooperative class CE: one wave per object cell, 80 logits gathered
    // by 40 lanes in parallel (one memory latency, not a serial chain)
    const int ne = n_obj;
    for (int e = wid; e < ne; e += 4) {
        int pk    = entries[e];
        int ecell = pk & 0xFFFF;
        int ecls  = pk >> 16;
        int ea  = ecell / HW;
        int ehw = ecell - ea * HW;
        const float* cl = out + ((size_t)(b * NUM_ANCHORS + ea) * CH + 5) * HW + ehw;
        float v0 = (lane < NUM_CLASSES / 2) ? cl[(2 * lane + 0) * HW] : -INFINITY;
        float v1 = (lane < NUM_CLASSES / 2) ? cl[(2 * lane + 1) * HW] : -INFINITY;
        float m = fmaxf(v0, v1);
        #pragma unroll
        for (int off = 32; off > 0; off >>= 1)
            m = fmaxf(m, __shfl_xor(m, off, 64));
        float s = (lane < NUM_CLASSES / 2)
                    ? (__expf(v0 - m) + __expf(v1 - m)) : 0.0f;
        #pragma unroll
        for (int off = 32; off > 0; off >>= 1)
            s += __shfl_xor(s, off, 64);
        // target logit via shuffle from its owner lane (ecls is wave-uniform)
        float tsel = (ecls & 1) ? v1 : v0;
        float tl = __shfl(tsel, ecls >> 1, 64);
        if (lane == 0) local += (m + __logf(s) - tl);
    }

    // wave reduce, cross-wave via LDS, one partial per block (deterministic)
    #pragma unroll
    for (int off = 32; off > 0; off >>= 1)
        local += __shfl_down(local, off, 64);
    if (lane == 0) wsum[wid] = local;
    __syncthreads();
    if (threadIdx.x == 0)
        partial[blockIdx.x] = wsum[0] + wsum[1] + wsum[2] + wsum[3];
}

__global__ __launch_bounds__(256) void yolov2_reduce(
    const float* __restrict__ partial, int n, float* __restrict__ loss)
{
    __shared__ float wsum[4];
    float v = 0.0f;
    for (int i = threadIdx.x; i < n; i += 256) v += partial[i];
    #pragma unroll
    for (int off = 32; off > 0; off >>= 1)
        v += __shfl_down(v, off, 64);
    const int lane = threadIdx.x & 63;
    const int wid  = threadIdx.x >> 6;
    if (lane == 0) wsum[wid] = v;
    __syncthreads();
    if (threadIdx.x == 0) loss[0] = wsum[0] + wsum[1] + wsum[2] + wsum[3];
}

extern "C" void kernel_launch(void* const* d_in, const int* in_sizes, int n_in,
                              void* d_out, int out_size, void* d_ws, size_t ws_size,
                              hipStream_t stream) {
    const float* out_t   = (const float*)d_in[0];
    const float* target  = (const float*)d_in[1];
    const float* anchors = (const float*)d_in[2];
    float* loss    = (float*)d_out;
    float* partial = (float*)d_ws;

    const int B = in_sizes[1] / (MAX_OBJECT * 5);
    const int nblocks = B * BLOCKS_PER_B;

    yolov2_main<<<dim3(nblocks), dim3(256), 0, stream>>>(out_t, target, anchors, partial);
    yolov2_reduce<<<dim3(1), dim3(256), 0, stream>>>(partial, nblocks, loss);
}